// Round 7
// baseline (140.092 us; speedup 1.0000x reference)
//
#include <hip/hip_runtime.h>
#include <hip/hip_bf16.h>
#include <stdint.h>

#define NB 8
#define DIMG 2048
#define HWN 196
#define PN 1568
#define PPAD 1600
#define DMID 1024
#define NC 80
#define DWORD 300
#define PART 16

typedef short bf16x8 __attribute__((ext_vector_type(8)));
typedef float f32x4 __attribute__((ext_vector_type(4)));

__device__ __forceinline__ unsigned short f2bf(float x) {
  union { float f; unsigned u; } c; c.f = x;
  unsigned r = c.u + 0x7FFFu + ((c.u >> 16) & 1u);
  return (unsigned short)(r >> 16);
}

// tanh via CF-11 Pade: x*(10395+1260s+21s^2)/(10395+4725s+210s^2+s^3), s=x^2
// clamp |x|<=4.5 ; reciprocal via bit-trick + 2 Newton (no trans ops).
__device__ __forceinline__ float tanh_pade(float x) {
  float xc = fminf(fmaxf(x, -4.5f), 4.5f);
  float s = xc * xc;
  float n = fmaf(s, 21.f, 1260.f);
  n = fmaf(s, n, 10395.f);
  float d = s + 210.f;
  d = fmaf(s, d, 4725.f);
  d = fmaf(s, d, 10395.f);
  union { float f; unsigned u; } c; c.f = d;
  c.u = 0x7EF311C3u - c.u;
  float y = c.f;
  y = y * fmaf(-d, y, 2.f);
  y = y * fmaf(-d, y, 2.f);
  return xc * n * y;
}

// ---------------------------------------------------------------- transpose + W1 cvt (merged)
__global__ void k_tc(const float* __restrict__ img, float* __restrict__ fmap,
                     unsigned short* __restrict__ fmapH,
                     const float* __restrict__ W1, unsigned short* __restrict__ W1h) {
  __shared__ float tile[32][33];
  int bx = blockIdx.x;
  int tx = threadIdx.x, ty = threadIdx.y;
  if (bx < 3584) {
    int d0 = (bx & 63) * 32;
    int rem = bx >> 6;
    int h0 = (rem % 7) * 32, b = rem / 7;
    const float* src = img + (size_t)b * DIMG * HWN;
#pragma unroll
    for (int i = 0; i < 32; i += 8) {
      int hw = h0 + tx;
      tile[ty + i][tx] = (hw < HWN) ? src[(size_t)(d0 + ty + i) * HWN + hw] : 0.f;
    }
    __syncthreads();
#pragma unroll
    for (int i = 0; i < 32; i += 8) {
      int hw = h0 + ty + i;
      if (hw < HWN) {
        float v = tile[tx][ty + i];
        size_t o = (size_t)(b * HWN + hw) * DIMG + d0 + tx;
        fmap[o] = v;
        fmapH[o] = f2bf(v);
      }
    }
  } else {
    int tid = ty * 32 + tx;
    int i = ((bx - 3584) * 256 + tid) * 4;
    f32x4 v = *(const f32x4*)(W1 + i);
    ushort4 s;
    s.x = f2bf(v[0]); s.y = f2bf(v[1]); s.z = f2bf(v[2]); s.w = f2bf(v[3]);
    *(ushort4*)(W1h + i) = s;
  }
}

// ---------------------------------------------------------------- fwd + weff (coalesced, LDS-staged)
// fwd[c][m] = sum_k word[c][k]*W2[m][k]   (RAW, no prescale — poly-tanh path)
__global__ __launch_bounds__(256) void k_fwdweff(const float* __restrict__ word,
                                                 const float* __restrict__ W2,
                                                 float* __restrict__ fwd,
                                                 const float* __restrict__ Wa,
                                                 const float* __restrict__ W3,
                                                 float* __restrict__ partial) {
  __shared__ __align__(16) float w2s[64 * DWORD];   // 76.8 KB
  __shared__ __align__(16) float wds[16 * DWORD];   // 19.2 KB
  int bx = blockIdx.x, t = threadIdx.x;
  if (bx < 80) {
    int m0 = (bx & 15) * 64, c0 = (bx >> 4) * 16;
    for (int u = t; u < 64 * 75; u += 256) {
      int r = u / 75, q = u - r * 75;
      *(f32x4*)&w2s[r * DWORD + q * 4] =
          *(const f32x4*)(W2 + (size_t)(m0 + r) * DWORD + q * 4);
    }
    for (int u = t; u < 16 * 75; u += 256) {
      int r = u / 75, q = u - r * 75;
      *(f32x4*)&wds[r * DWORD + q * 4] =
          *(const f32x4*)(word + (size_t)(c0 + r) * DWORD + q * 4);
    }
    __syncthreads();
    int ci = t >> 4, mi = t & 15;
    f32x4 a0 = {0.f, 0.f, 0.f, 0.f}, a1 = a0, a2 = a0, a3 = a0;
    const float* wr = &wds[ci * DWORD];
    for (int q = 0; q < 75; ++q) {
      f32x4 wv = *(const f32x4*)&wr[q * 4];
      f32x4 b0 = *(const f32x4*)&w2s[(mi)*DWORD + q * 4];
      f32x4 b1 = *(const f32x4*)&w2s[(mi + 16) * DWORD + q * 4];
      f32x4 b2 = *(const f32x4*)&w2s[(mi + 32) * DWORD + q * 4];
      f32x4 b3 = *(const f32x4*)&w2s[(mi + 48) * DWORD + q * 4];
#pragma unroll
      for (int u = 0; u < 4; ++u) {
        a0[u] = fmaf(wv[u], b0[u], a0[u]);
        a1[u] = fmaf(wv[u], b1[u], a1[u]);
        a2[u] = fmaf(wv[u], b2[u], a2[u]);
        a3[u] = fmaf(wv[u], b3[u], a3[u]);
      }
    }
    float* dst = fwd + (size_t)(c0 + ci) * DMID + m0 + mi;
    dst[0]  = a0[0] + a0[1] + a0[2] + a0[3];
    dst[16] = a1[0] + a1[1] + a1[2] + a1[3];
    dst[32] = a2[0] + a2[1] + a2[2] + a2[3];
    dst[48] = a3[0] + a3[1] + a3[2] + a3[3];
  } else {
    int idx = bx - 80;
    int m = (idx & 3) * 256 + t;
    int n0 = (idx >> 2) * 64;
    float acc = 0.f;
    for (int n = n0; n < n0 + 64; ++n) acc = fmaf(Wa[n], W3[(size_t)n * DMID + m], acc);
    partial[(size_t)(idx >> 2) * DMID + m] = acc;
  }
}

// ---------------------------------------------------------------- GEMM: fwh[1600][1024] = fmapH x W1h^T
#define GLDS(g, l) \
  __builtin_amdgcn_global_load_lds((const __attribute__((address_space(1))) void*)(g), \
                                   (__attribute__((address_space(3))) void*)(l), 16, 0, 0)

__global__ __launch_bounds__(256) void k_gemm(const unsigned short* __restrict__ A,
                                              const unsigned short* __restrict__ Bw,
                                              float* __restrict__ C) {
  __shared__ __align__(16) unsigned short As[3][64 * 64];
  __shared__ __align__(16) unsigned short Bs[3][64 * 64];
  int m0 = blockIdx.x * 64, n0 = blockIdx.y * 64;
  int t = threadIdx.x;
  int w = t >> 6, l = t & 63;
  int wr = w >> 1, wc = w & 1;
  f32x4 zero = {0.f, 0.f, 0.f, 0.f};
  f32x4 acc00 = zero, acc01 = zero, acc10 = zero, acc11 = zero;

  int r0 = t >> 3, c0 = t & 7;
  int r1 = r0 + 32;
  const unsigned short* ga0 = A + (size_t)(m0 + r0) * 2048 + ((c0 ^ (r0 & 7)) << 3);
  const unsigned short* ga1 = A + (size_t)(m0 + r1) * 2048 + ((c0 ^ (r1 & 7)) << 3);
  const unsigned short* gb0 = Bw + (size_t)(n0 + r0) * 2048 + ((c0 ^ (r0 & 7)) << 3);
  const unsigned short* gb1 = Bw + (size_t)(n0 + r1) * 2048 + ((c0 ^ (r1 & 7)) << 3);

  int ra = wr * 32 + (l & 15);
  int rb = wc * 32 + (l & 15);
  int cc = l >> 4;
  int a_k0 = ra * 64 + (((cc) ^ (ra & 7)) << 3);
  int a_k1 = ra * 64 + (((cc + 4) ^ (ra & 7)) << 3);
  int b_k0 = rb * 64 + (((cc) ^ (rb & 7)) << 3);
  int b_k1 = rb * 64 + (((cc + 4) ^ (rb & 7)) << 3);

#define STAGE(bi, kk) do { \
    GLDS(ga0 + (kk), &As[bi][t * 8]); \
    GLDS(ga1 + (kk), &As[bi][t * 8 + 2048]); \
    GLDS(gb0 + (kk), &Bs[bi][t * 8]); \
    GLDS(gb1 + (kk), &Bs[bi][t * 8 + 2048]); \
  } while (0)

#define COMPUTE(bi) do { \
    const unsigned short* ap = As[bi]; \
    const unsigned short* bp = Bs[bi]; \
    bf16x8 A0 = *(const bf16x8*)(ap + a_k0); \
    bf16x8 A1 = *(const bf16x8*)(ap + a_k0 + 1024); \
    bf16x8 B0 = *(const bf16x8*)(bp + b_k0); \
    bf16x8 B1 = *(const bf16x8*)(bp + b_k0 + 1024); \
    acc00 = __builtin_amdgcn_mfma_f32_16x16x32_bf16(A0, B0, acc00, 0, 0, 0); \
    acc01 = __builtin_amdgcn_mfma_f32_16x16x32_bf16(A0, B1, acc01, 0, 0, 0); \
    acc10 = __builtin_amdgcn_mfma_f32_16x16x32_bf16(A1, B0, acc10, 0, 0, 0); \
    acc11 = __builtin_amdgcn_mfma_f32_16x16x32_bf16(A1, B1, acc11, 0, 0, 0); \
    bf16x8 A2 = *(const bf16x8*)(ap + a_k1); \
    bf16x8 A3 = *(const bf16x8*)(ap + a_k1 + 1024); \
    bf16x8 B2 = *(const bf16x8*)(bp + b_k1); \
    bf16x8 B3 = *(const bf16x8*)(bp + b_k1 + 1024); \
    acc00 = __builtin_amdgcn_mfma_f32_16x16x32_bf16(A2, B2, acc00, 0, 0, 0); \
    acc01 = __builtin_amdgcn_mfma_f32_16x16x32_bf16(A2, B3, acc01, 0, 0, 0); \
    acc10 = __builtin_amdgcn_mfma_f32_16x16x32_bf16(A3, B2, acc10, 0, 0, 0); \
    acc11 = __builtin_amdgcn_mfma_f32_16x16x32_bf16(A3, B3, acc11, 0, 0, 0); \
  } while (0)

  STAGE(0, 0);
  STAGE(1, 64);
  asm volatile("s_waitcnt vmcnt(4)" ::: "memory");
  __builtin_amdgcn_s_barrier();
  __builtin_amdgcn_sched_barrier(0);
  for (int kt = 0; kt < 32; ++kt) {
    int cur = kt % 3;
    if (kt < 30) STAGE((kt + 2) % 3, (kt + 2) * 64);
    COMPUTE(cur);
    if (kt < 30) {
      asm volatile("s_waitcnt vmcnt(4)" ::: "memory");
      __builtin_amdgcn_s_barrier();
      __builtin_amdgcn_sched_barrier(0);
    } else if (kt == 30) {
      asm volatile("s_waitcnt vmcnt(0)" ::: "memory");
      __builtin_amdgcn_s_barrier();
      __builtin_amdgcn_sched_barrier(0);
    }
  }
  int cr = (l >> 4) << 2, ccn = l & 15;
#pragma unroll
  for (int q = 0; q < 4; ++q) {
    C[(size_t)(m0 + wr * 32 + cr + q) * DMID + n0 + wc * 32 + ccn] = acc00[q];
    C[(size_t)(m0 + wr * 32 + cr + q) * DMID + n0 + wc * 32 + 16 + ccn] = acc01[q];
    C[(size_t)(m0 + wr * 32 + 16 + cr + q) * DMID + n0 + wc * 32 + ccn] = acc10[q];
    C[(size_t)(m0 + wr * 32 + 16 + cr + q) * DMID + n0 + wc * 32 + 16 + ccn] = acc11[q];
  }
#undef STAGE
#undef COMPUTE
}

// ---------------------------------------------------------------- coef logits, poly-tanh (NO transcendentals)
// tile: 64p x 16c x 64m per block; thread (pi,ci): p = p0+pi+16j (j<4), c = c0+ci
#define MC 64
__global__ __launch_bounds__(256) void k_coef(const float* __restrict__ fwh,
                                              const float* __restrict__ fwd,
                                              const float* __restrict__ partial,
                                              float* __restrict__ coefp) {
  __shared__ __align__(16) float al[64][68];   // 17.4 KB
  __shared__ __align__(16) float bl[16][68];   //  4.3 KB
  __shared__ __align__(16) float wl[MC];
  int p0 = blockIdx.x * 64, c0 = blockIdx.y * 16, mz = blockIdx.z;
  int mbase = mz * MC;
  int t = threadIdx.x;
  // ---- stage
  {
    int sra = t >> 2, sca = (t & 3) << 4;   // al: 4 x f32x4 per thread
    const float* gA = fwh + (size_t)(p0 + sra) * DMID + mbase + sca;
#pragma unroll
    for (int q = 0; q < 4; ++q)
      *(f32x4*)&al[sra][sca + q * 4] = *(const f32x4*)&gA[q * 4];
    int srb = t >> 4, scb = (t & 15) << 2;  // bl: 1 x f32x4 per thread
    *(f32x4*)&bl[srb][scb] = *(const f32x4*)(fwd + (size_t)(c0 + srb) * DMID + mbase + scb);
    if (t < MC) {                           // wl[m] = sum_s partial[s][m]
      float v = 0.f;
#pragma unroll
      for (int s = 0; s < 16; ++s) v += partial[(size_t)s * DMID + mbase + t];
      wl[t] = v;
    }
  }
  __syncthreads();
  int pi = t >> 4, ci = t & 15;
  float acc[4];
#pragma unroll
  for (int j = 0; j < 4; ++j) acc[j] = 0.f;

  for (int mm = 0; mm < MC; mm += 4) {
    f32x4 wv = *(const f32x4*)&wl[mm];
    f32x4 bv = *(const f32x4*)&bl[ci][mm];
    f32x4 av0 = *(const f32x4*)&al[pi][mm];
    f32x4 av1 = *(const f32x4*)&al[pi + 16][mm];
    f32x4 av2 = *(const f32x4*)&al[pi + 32][mm];
    f32x4 av3 = *(const f32x4*)&al[pi + 48][mm];
#pragma unroll
    for (int u = 0; u < 4; ++u) {
      float w = wv[u], b = bv[u];
      acc[0] = fmaf(w, tanh_pade(av0[u] * b), acc[0]);
      acc[1] = fmaf(w, tanh_pade(av1[u] * b), acc[1]);
      acc[2] = fmaf(w, tanh_pade(av2[u] * b), acc[2]);
      acc[3] = fmaf(w, tanh_pade(av3[u] * b), acc[3]);
    }
  }
  float* cp = coefp + (size_t)mz * (PN * NC);
#pragma unroll
  for (int j = 0; j < 4; ++j) {
    int p = p0 + pi + 16 * j;
    if (p < PN) cp[(size_t)p * NC + c0 + ci] = acc[j];
  }
}

// ---------------------------------------------------------------- softmax + pooling (merged); sums 16 coef partials
__global__ __launch_bounds__(256) void k_pool(const float* __restrict__ coefp,
                                              const float* __restrict__ fmap,
                                              float* __restrict__ out) {
  __shared__ __align__(16) float wt[HWN][16];
  __shared__ float red[16][16];
  __shared__ float mxs[16], inv[16];
  int dc = blockIdx.x * 256, cg = blockIdx.y * 16, b = blockIdx.z;
  int t = threadIdx.x;
  for (int i = t; i < HWN * 4; i += 256) {
    int hw = i >> 2, j4 = (i & 3) << 2;
    size_t o = (size_t)(b * HWN + hw) * NC + cg + j4;
    f32x4 s = {0.f, 0.f, 0.f, 0.f};
#pragma unroll
    for (int z = 0; z < PART; ++z) s += *(const f32x4*)&coefp[o + (size_t)z * (PN * NC)];
    *(f32x4*)&wt[hw][j4] = s;
  }
  __syncthreads();
  int j = t & 15, g = t >> 4;
  float pm = -1e30f;
  for (int hw = g; hw < HWN; hw += 16) pm = fmaxf(pm, wt[hw][j]);
  red[g][j] = pm;
  __syncthreads();
  if (t < 16) {
    float m = red[0][t];
#pragma unroll
    for (int g2 = 1; g2 < 16; ++g2) m = fmaxf(m, red[g2][t]);
    mxs[t] = m;
  }
  __syncthreads();
  float mj = mxs[j], ps = 0.f;
  for (int hw = g; hw < HWN; hw += 16) {
    float e = __builtin_amdgcn_exp2f((wt[hw][j] - mj) * 1.4426950408889634f);
    wt[hw][j] = e;
    ps += e;
  }
  red[g][j] = ps;
  __syncthreads();
  if (t < 16) {
    float s = 0.f;
#pragma unroll
    for (int g2 = 0; g2 < 16; ++g2) s += red[g2][t];
    inv[t] = 1.f / s;
  }
  __syncthreads();
  float acc[16];
#pragma unroll
  for (int q = 0; q < 16; ++q) acc[q] = 0.f;
  const float* fp = fmap + (size_t)b * HWN * DIMG + dc + t;
  for (int hw = 0; hw < HWN; ++hw) {
    float v = fp[(size_t)hw * DIMG];
#pragma unroll
    for (int q = 0; q < 16; ++q) acc[q] = fmaf(wt[hw][q], v, acc[q]);
  }
#pragma unroll
  for (int q = 0; q < 16; ++q)
    out[((size_t)b * NC + cg + q) * DIMG + dc + t] = acc[q] * inv[q];
}

// ----------------------------------------------------------------
extern "C" void kernel_launch(void* const* d_in, const int* in_sizes, int n_in,
                              void* d_out, int out_size, void* d_ws, size_t ws_size,
                              hipStream_t stream) {
  const float* img  = (const float*)d_in[1];
  const float* word = (const float*)d_in[2];
  const float* W1   = (const float*)d_in[3];
  const float* W2   = (const float*)d_in[4];
  const float* W3   = (const float*)d_in[5];
  const float* Wa   = (const float*)d_in[7];
  // b3 (d_in[6]) and ba (d_in[8]) are softmax-shift-invariant -> dropped.
  float* out = (float*)d_out;
  char* ws = (char*)d_ws;

  float*          fmap    = (float*)(ws + 0);                  // 12,845,056
  unsigned short* fmapH   = (unsigned short*)(ws + 12845056);  //  6,553,600
  unsigned short* W1h     = (unsigned short*)(ws + 19398656);  //  4,194,304
  float*          fwh     = (float*)(ws + 23592960);           //  6,553,600
  float*          fwd     = (float*)(ws + 30146560);           //    393,216
  float*          partial = (float*)(ws + 30539776);           //     65,536
  float*          coefp   = (float*)(ws + 30605312);           // 16*1568*80*4 = 8,028,160

  hipLaunchKernelGGL(k_tc, dim3(5632), dim3(32, 8), 0, stream, img, fmap, fmapH, W1, W1h);
  hipLaunchKernelGGL(k_fwdweff, dim3(144), dim3(256), 0, stream,
                     word, W2, fwd, Wa, W3, partial);
  hipLaunchKernelGGL(k_gemm, dim3(25, 16), dim3(256), 0, stream, fmapH, W1h, fwh);
  hipLaunchKernelGGL(k_coef, dim3(25, 5, 16), dim3(256), 0, stream, fwh, fwd, partial, coefp);
  hipLaunchKernelGGL(k_pool, dim3(8, 5, 8), dim3(256), 0, stream, coefp, fmap, out);
  (void)in_sizes; (void)n_in; (void)out_size; (void)ws_size;
}

// Round 8
// 119.589 us; speedup vs baseline: 1.1714x; 1.1714x over previous
//
#include <hip/hip_runtime.h>
#include <hip/hip_bf16.h>
#include <stdint.h>

#define NB 8
#define DIMG 2048
#define HWN 196
#define PN 1568
#define PPAD 1600
#define DMID 1024
#define NC 80
#define DWORD 300
#define PART 16

typedef short bf16x8 __attribute__((ext_vector_type(8)));
typedef float f32x4 __attribute__((ext_vector_type(4)));

__device__ __forceinline__ unsigned short f2bf(float x) {
  union { float f; unsigned u; } c; c.f = x;
  unsigned r = c.u + 0x7FFFu + ((c.u >> 16) & 1u);
  return (unsigned short)(r >> 16);
}

// ---------------------------------------------------------------- transpose + W1 cvt (merged)
__global__ void k_tc(const float* __restrict__ img, float* __restrict__ fmap,
                     unsigned short* __restrict__ fmapH,
                     const float* __restrict__ W1, unsigned short* __restrict__ W1h) {
  __shared__ float tile[32][33];
  int bx = blockIdx.x;
  int tx = threadIdx.x, ty = threadIdx.y;
  if (bx < 3584) {
    int d0 = (bx & 63) * 32;
    int rem = bx >> 6;
    int h0 = (rem % 7) * 32, b = rem / 7;
    const float* src = img + (size_t)b * DIMG * HWN;
#pragma unroll
    for (int i = 0; i < 32; i += 8) {
      int hw = h0 + tx;
      tile[ty + i][tx] = (hw < HWN) ? src[(size_t)(d0 + ty + i) * HWN + hw] : 0.f;
    }
    __syncthreads();
#pragma unroll
    for (int i = 0; i < 32; i += 8) {
      int hw = h0 + ty + i;
      if (hw < HWN) {
        float v = tile[tx][ty + i];
        size_t o = (size_t)(b * HWN + hw) * DIMG + d0 + tx;
        fmap[o] = v;
        fmapH[o] = f2bf(v);
      }
    }
  } else {
    int tid = ty * 32 + tx;
    int i = ((bx - 3584) * 256 + tid) * 4;
    f32x4 v = *(const f32x4*)(W1 + i);
    ushort4 s;
    s.x = f2bf(v[0]); s.y = f2bf(v[1]); s.z = f2bf(v[2]); s.w = f2bf(v[3]);
    *(ushort4*)(W1h + i) = s;
  }
}

// ---------------------------------------------------------------- fwd + weff (coalesced, LDS-staged)
// fwd[c][m] = SC * sum_k word[c][k]*W2[m][k]  (SC = 2*log2e, sigmoid-form prescale)
__global__ __launch_bounds__(256) void k_fwdweff(const float* __restrict__ word,
                                                 const float* __restrict__ W2,
                                                 float* __restrict__ fwd,
                                                 const float* __restrict__ Wa,
                                                 const float* __restrict__ W3,
                                                 float* __restrict__ partial) {
  __shared__ __align__(16) float w2s[64 * DWORD];   // 76.8 KB
  __shared__ __align__(16) float wds[16 * DWORD];   // 19.2 KB
  int bx = blockIdx.x, t = threadIdx.x;
  if (bx < 80) {
    int m0 = (bx & 15) * 64, c0 = (bx >> 4) * 16;
    const float SC = 2.8853900817779268f;  // 2*log2(e)
    for (int u = t; u < 64 * 75; u += 256) {
      int r = u / 75, q = u - r * 75;
      *(f32x4*)&w2s[r * DWORD + q * 4] =
          *(const f32x4*)(W2 + (size_t)(m0 + r) * DWORD + q * 4);
    }
    for (int u = t; u < 16 * 75; u += 256) {
      int r = u / 75, q = u - r * 75;
      f32x4 v = *(const f32x4*)(word + (size_t)(c0 + r) * DWORD + q * 4);
      *(f32x4*)&wds[r * DWORD + q * 4] = v * SC;
    }
    __syncthreads();
    int ci = t >> 4, mi = t & 15;
    f32x4 a0 = {0.f, 0.f, 0.f, 0.f}, a1 = a0, a2 = a0, a3 = a0;
    const float* wr = &wds[ci * DWORD];
    for (int q = 0; q < 75; ++q) {
      f32x4 wv = *(const f32x4*)&wr[q * 4];
      f32x4 b0 = *(const f32x4*)&w2s[(mi)*DWORD + q * 4];
      f32x4 b1 = *(const f32x4*)&w2s[(mi + 16) * DWORD + q * 4];
      f32x4 b2 = *(const f32x4*)&w2s[(mi + 32) * DWORD + q * 4];
      f32x4 b3 = *(const f32x4*)&w2s[(mi + 48) * DWORD + q * 4];
#pragma unroll
      for (int u = 0; u < 4; ++u) {
        a0[u] = fmaf(wv[u], b0[u], a0[u]);
        a1[u] = fmaf(wv[u], b1[u], a1[u]);
        a2[u] = fmaf(wv[u], b2[u], a2[u]);
        a3[u] = fmaf(wv[u], b3[u], a3[u]);
      }
    }
    float* dst = fwd + (size_t)(c0 + ci) * DMID + m0 + mi;
    dst[0]  = a0[0] + a0[1] + a0[2] + a0[3];
    dst[16] = a1[0] + a1[1] + a1[2] + a1[3];
    dst[32] = a2[0] + a2[1] + a2[2] + a2[3];
    dst[48] = a3[0] + a3[1] + a3[2] + a3[3];
  } else {
    int idx = bx - 80;
    int m = (idx & 3) * 256 + t;
    int n0 = (idx >> 2) * 64;
    float acc = 0.f;
    for (int n = n0; n < n0 + 64; ++n) acc = fmaf(Wa[n], W3[(size_t)n * DMID + m], acc);
    partial[(size_t)(idx >> 2) * DMID + m] = acc;
  }
}

// ---------------------------------------------------------------- GEMM: fwh[1600][1024] = fmapH x W1h^T
#define GLDS(g, l) \
  __builtin_amdgcn_global_load_lds((const __attribute__((address_space(1))) void*)(g), \
                                   (__attribute__((address_space(3))) void*)(l), 16, 0, 0)

__global__ __launch_bounds__(256) void k_gemm(const unsigned short* __restrict__ A,
                                              const unsigned short* __restrict__ Bw,
                                              float* __restrict__ C) {
  __shared__ __align__(16) unsigned short As[3][64 * 64];
  __shared__ __align__(16) unsigned short Bs[3][64 * 64];
  int m0 = blockIdx.x * 64, n0 = blockIdx.y * 64;
  int t = threadIdx.x;
  int w = t >> 6, l = t & 63;
  int wr = w >> 1, wc = w & 1;
  f32x4 zero = {0.f, 0.f, 0.f, 0.f};
  f32x4 acc00 = zero, acc01 = zero, acc10 = zero, acc11 = zero;

  int r0 = t >> 3, c0 = t & 7;
  int r1 = r0 + 32;
  const unsigned short* ga0 = A + (size_t)(m0 + r0) * 2048 + ((c0 ^ (r0 & 7)) << 3);
  const unsigned short* ga1 = A + (size_t)(m0 + r1) * 2048 + ((c0 ^ (r1 & 7)) << 3);
  const unsigned short* gb0 = Bw + (size_t)(n0 + r0) * 2048 + ((c0 ^ (r0 & 7)) << 3);
  const unsigned short* gb1 = Bw + (size_t)(n0 + r1) * 2048 + ((c0 ^ (r1 & 7)) << 3);

  int ra = wr * 32 + (l & 15);
  int rb = wc * 32 + (l & 15);
  int cc = l >> 4;
  int a_k0 = ra * 64 + (((cc) ^ (ra & 7)) << 3);
  int a_k1 = ra * 64 + (((cc + 4) ^ (ra & 7)) << 3);
  int b_k0 = rb * 64 + (((cc) ^ (rb & 7)) << 3);
  int b_k1 = rb * 64 + (((cc + 4) ^ (rb & 7)) << 3);

#define STAGE(bi, kk) do { \
    GLDS(ga0 + (kk), &As[bi][t * 8]); \
    GLDS(ga1 + (kk), &As[bi][t * 8 + 2048]); \
    GLDS(gb0 + (kk), &Bs[bi][t * 8]); \
    GLDS(gb1 + (kk), &Bs[bi][t * 8 + 2048]); \
  } while (0)

#define COMPUTE(bi) do { \
    const unsigned short* ap = As[bi]; \
    const unsigned short* bp = Bs[bi]; \
    bf16x8 A0 = *(const bf16x8*)(ap + a_k0); \
    bf16x8 A1 = *(const bf16x8*)(ap + a_k0 + 1024); \
    bf16x8 B0 = *(const bf16x8*)(bp + b_k0); \
    bf16x8 B1 = *(const bf16x8*)(bp + b_k0 + 1024); \
    acc00 = __builtin_amdgcn_mfma_f32_16x16x32_bf16(A0, B0, acc00, 0, 0, 0); \
    acc01 = __builtin_amdgcn_mfma_f32_16x16x32_bf16(A0, B1, acc01, 0, 0, 0); \
    acc10 = __builtin_amdgcn_mfma_f32_16x16x32_bf16(A1, B0, acc10, 0, 0, 0); \
    acc11 = __builtin_amdgcn_mfma_f32_16x16x32_bf16(A1, B1, acc11, 0, 0, 0); \
    bf16x8 A2 = *(const bf16x8*)(ap + a_k1); \
    bf16x8 A3 = *(const bf16x8*)(ap + a_k1 + 1024); \
    bf16x8 B2 = *(const bf16x8*)(bp + b_k1); \
    bf16x8 B3 = *(const bf16x8*)(bp + b_k1 + 1024); \
    acc00 = __builtin_amdgcn_mfma_f32_16x16x32_bf16(A2, B2, acc00, 0, 0, 0); \
    acc01 = __builtin_amdgcn_mfma_f32_16x16x32_bf16(A2, B3, acc01, 0, 0, 0); \
    acc10 = __builtin_amdgcn_mfma_f32_16x16x32_bf16(A3, B2, acc10, 0, 0, 0); \
    acc11 = __builtin_amdgcn_mfma_f32_16x16x32_bf16(A3, B3, acc11, 0, 0, 0); \
  } while (0)

  STAGE(0, 0);
  STAGE(1, 64);
  asm volatile("s_waitcnt vmcnt(4)" ::: "memory");
  __builtin_amdgcn_s_barrier();
  __builtin_amdgcn_sched_barrier(0);
  for (int kt = 0; kt < 32; ++kt) {
    int cur = kt % 3;
    if (kt < 30) STAGE((kt + 2) % 3, (kt + 2) * 64);
    COMPUTE(cur);
    if (kt < 30) {
      asm volatile("s_waitcnt vmcnt(4)" ::: "memory");
      __builtin_amdgcn_s_barrier();
      __builtin_amdgcn_sched_barrier(0);
    } else if (kt == 30) {
      asm volatile("s_waitcnt vmcnt(0)" ::: "memory");
      __builtin_amdgcn_s_barrier();
      __builtin_amdgcn_sched_barrier(0);
    }
  }
  int cr = (l >> 4) << 2, ccn = l & 15;
#pragma unroll
  for (int q = 0; q < 4; ++q) {
    C[(size_t)(m0 + wr * 32 + cr + q) * DMID + n0 + wc * 32 + ccn] = acc00[q];
    C[(size_t)(m0 + wr * 32 + cr + q) * DMID + n0 + wc * 32 + 16 + ccn] = acc01[q];
    C[(size_t)(m0 + wr * 32 + 16 + cr + q) * DMID + n0 + wc * 32 + ccn] = acc10[q];
    C[(size_t)(m0 + wr * 32 + 16 + cr + q) * DMID + n0 + wc * 32 + 16 + ccn] = acc11[q];
  }
#undef STAGE
#undef COMPUTE
}

// ---------------------------------------------------------------- coef logits, sigmoid-form (exp2+rcp), R7 structure
// tile: 64p x 16c x 64m per block; thread (pi,ci): p = p0+pi+16j (j<4), c = c0+ci
// coefp contribution = sum_m (-2 w_eff[m]) / (1 + e^{2 x}),  x = fwh*fwd_raw
#define MC 64
__global__ __launch_bounds__(256) void k_coef(const float* __restrict__ fwh,
                                              const float* __restrict__ fwd,
                                              const float* __restrict__ partial,
                                              float* __restrict__ coefp) {
  __shared__ __align__(16) float al[64][68];   // 17.4 KB
  __shared__ __align__(16) float bl[16][68];   //  4.3 KB
  __shared__ __align__(16) float wl[MC];
  int p0 = blockIdx.x * 64, c0 = blockIdx.y * 16, mz = blockIdx.z;
  int mbase = mz * MC;
  int t = threadIdx.x;
  // ---- stage
  {
    int sra = t >> 2, sca = (t & 3) << 4;   // al: 4 x f32x4 per thread
    const float* gA = fwh + (size_t)(p0 + sra) * DMID + mbase + sca;
#pragma unroll
    for (int q = 0; q < 4; ++q)
      *(f32x4*)&al[sra][sca + q * 4] = *(const f32x4*)&gA[q * 4];
    int srb = t >> 4, scb = (t & 15) << 2;  // bl: 1 x f32x4 per thread
    *(f32x4*)&bl[srb][scb] = *(const f32x4*)(fwd + (size_t)(c0 + srb) * DMID + mbase + scb);
    if (t < MC) {                           // wl[m] = -2 * sum_s partial[s][m]
      float v = 0.f;
#pragma unroll
      for (int s = 0; s < 16; ++s) v += partial[(size_t)s * DMID + mbase + t];
      wl[t] = -2.f * v;
    }
  }
  __syncthreads();
  int pi = t >> 4, ci = t & 15;
  float acc[4];
#pragma unroll
  for (int j = 0; j < 4; ++j) acc[j] = 0.f;

  for (int mm = 0; mm < MC; mm += 4) {
    f32x4 wv = *(const f32x4*)&wl[mm];
    f32x4 bv = *(const f32x4*)&bl[ci][mm];
    f32x4 av0 = *(const f32x4*)&al[pi][mm];
    f32x4 av1 = *(const f32x4*)&al[pi + 16][mm];
    f32x4 av2 = *(const f32x4*)&al[pi + 32][mm];
    f32x4 av3 = *(const f32x4*)&al[pi + 48][mm];
#pragma unroll
    for (int u = 0; u < 4; ++u) {
      float w = wv[u], b = bv[u];
      float e0 = __builtin_amdgcn_exp2f(av0[u] * b);
      float e1 = __builtin_amdgcn_exp2f(av1[u] * b);
      float e2 = __builtin_amdgcn_exp2f(av2[u] * b);
      float e3 = __builtin_amdgcn_exp2f(av3[u] * b);
      acc[0] = fmaf(w, __builtin_amdgcn_rcpf(1.f + e0), acc[0]);
      acc[1] = fmaf(w, __builtin_amdgcn_rcpf(1.f + e1), acc[1]);
      acc[2] = fmaf(w, __builtin_amdgcn_rcpf(1.f + e2), acc[2]);
      acc[3] = fmaf(w, __builtin_amdgcn_rcpf(1.f + e3), acc[3]);
    }
  }
  float* cp = coefp + (size_t)mz * (PN * NC);
#pragma unroll
  for (int j = 0; j < 4; ++j) {
    int p = p0 + pi + 16 * j;
    if (p < PN) cp[(size_t)p * NC + c0 + ci] = acc[j];
  }
}

// ---------------------------------------------------------------- softmax + pooling (merged); sums 16 coef partials
__global__ __launch_bounds__(256) void k_pool(const float* __restrict__ coefp,
                                              const float* __restrict__ fmap,
                                              float* __restrict__ out) {
  __shared__ __align__(16) float wt[HWN][16];
  __shared__ float red[16][16];
  __shared__ float mxs[16], inv[16];
  int dc = blockIdx.x * 256, cg = blockIdx.y * 16, b = blockIdx.z;
  int t = threadIdx.x;
  for (int i = t; i < HWN * 4; i += 256) {
    int hw = i >> 2, j4 = (i & 3) << 2;
    size_t o = (size_t)(b * HWN + hw) * NC + cg + j4;
    f32x4 s = {0.f, 0.f, 0.f, 0.f};
#pragma unroll
    for (int z = 0; z < PART; ++z) s += *(const f32x4*)&coefp[o + (size_t)z * (PN * NC)];
    *(f32x4*)&wt[hw][j4] = s;
  }
  __syncthreads();
  int j = t & 15, g = t >> 4;
  float pm = -1e30f;
  for (int hw = g; hw < HWN; hw += 16) pm = fmaxf(pm, wt[hw][j]);
  red[g][j] = pm;
  __syncthreads();
  if (t < 16) {
    float m = red[0][t];
#pragma unroll
    for (int g2 = 1; g2 < 16; ++g2) m = fmaxf(m, red[g2][t]);
    mxs[t] = m;
  }
  __syncthreads();
  float mj = mxs[j], ps = 0.f;
  for (int hw = g; hw < HWN; hw += 16) {
    float e = __builtin_amdgcn_exp2f((wt[hw][j] - mj) * 1.4426950408889634f);
    wt[hw][j] = e;
    ps += e;
  }
  red[g][j] = ps;
  __syncthreads();
  if (t < 16) {
    float s = 0.f;
#pragma unroll
    for (int g2 = 0; g2 < 16; ++g2) s += red[g2][t];
    inv[t] = 1.f / s;
  }
  __syncthreads();
  float acc[16];
#pragma unroll
  for (int q = 0; q < 16; ++q) acc[q] = 0.f;
  const float* fp = fmap + (size_t)b * HWN * DIMG + dc + t;
  for (int hw = 0; hw < HWN; ++hw) {
    float v = fp[(size_t)hw * DIMG];
#pragma unroll
    for (int q = 0; q < 16; ++q) acc[q] = fmaf(wt[hw][q], v, acc[q]);
  }
#pragma unroll
  for (int q = 0; q < 16; ++q)
    out[((size_t)b * NC + cg + q) * DIMG + dc + t] = acc[q] * inv[q];
}

// ----------------------------------------------------------------
extern "C" void kernel_launch(void* const* d_in, const int* in_sizes, int n_in,
                              void* d_out, int out_size, void* d_ws, size_t ws_size,
                              hipStream_t stream) {
  const float* img  = (const float*)d_in[1];
  const float* word = (const float*)d_in[2];
  const float* W1   = (const float*)d_in[3];
  const float* W2   = (const float*)d_in[4];
  const float* W3   = (const float*)d_in[5];
  const float* Wa   = (const float*)d_in[7];
  // b3 (d_in[6]) and ba (d_in[8]) are softmax-shift-invariant -> dropped.
  float* out = (float*)d_out;
  char* ws = (char*)d_ws;

  float*          fmap    = (float*)(ws + 0);                  // 12,845,056
  unsigned short* fmapH   = (unsigned short*)(ws + 12845056);  //  6,553,600
  unsigned short* W1h     = (unsigned short*)(ws + 19398656);  //  4,194,304
  float*          fwh     = (float*)(ws + 23592960);           //  6,553,600
  float*          fwd     = (float*)(ws + 30146560);           //    393,216
  float*          partial = (float*)(ws + 30539776);           //     65,536
  float*          coefp   = (float*)(ws + 30605312);           // 16*1568*80*4 = 8,028,160

  hipLaunchKernelGGL(k_tc, dim3(5632), dim3(32, 8), 0, stream, img, fmap, fmapH, W1, W1h);
  hipLaunchKernelGGL(k_fwdweff, dim3(144), dim3(256), 0, stream,
                     word, W2, fwd, Wa, W3, partial);
  hipLaunchKernelGGL(k_gemm, dim3(25, 16), dim3(256), 0, stream, fmapH, W1h, fwh);
  hipLaunchKernelGGL(k_coef, dim3(25, 5, 16), dim3(256), 0, stream, fwh, fwd, partial, coefp);
  hipLaunchKernelGGL(k_pool, dim3(8, 5, 8), dim3(256), 0, stream, coefp, fmap, out);
  (void)in_sizes; (void)n_in; (void)out_size; (void)ws_size;
}

// Round 9
// 110.539 us; speedup vs baseline: 1.2673x; 1.0819x over previous
//
#include <hip/hip_runtime.h>
#include <hip/hip_bf16.h>
#include <stdint.h>

#define NB 8
#define DIMG 2048
#define HWN 196
#define PN 1568
#define PPAD 1600
#define DMID 1024
#define NC 80
#define DWORD 300
#define PART 16

typedef short bf16x8 __attribute__((ext_vector_type(8)));
typedef float f32x4 __attribute__((ext_vector_type(4)));

__device__ __forceinline__ unsigned short f2bf(float x) {
  union { float f; unsigned u; } c; c.f = x;
  unsigned r = c.u + 0x7FFFu + ((c.u >> 16) & 1u);
  return (unsigned short)(r >> 16);
}

// ---------------------------------------------------------------- transpose (bf16 only) + W1 cvt
__global__ void k_tc(const float* __restrict__ img, unsigned short* __restrict__ fmapH,
                     const float* __restrict__ W1, unsigned short* __restrict__ W1h) {
  __shared__ float tile[32][33];
  int bx = blockIdx.x;
  int tx = threadIdx.x, ty = threadIdx.y;
  if (bx < 3584) {
    int d0 = (bx & 63) * 32;
    int rem = bx >> 6;
    int h0 = (rem % 7) * 32, b = rem / 7;
    const float* src = img + (size_t)b * DIMG * HWN;
#pragma unroll
    for (int i = 0; i < 32; i += 8) {
      int hw = h0 + tx;
      tile[ty + i][tx] = (hw < HWN) ? src[(size_t)(d0 + ty + i) * HWN + hw] : 0.f;
    }
    __syncthreads();
#pragma unroll
    for (int i = 0; i < 32; i += 8) {
      int hw = h0 + ty + i;
      if (hw < HWN)
        fmapH[(size_t)(b * HWN + hw) * DIMG + d0 + tx] = f2bf(tile[tx][ty + i]);
    }
  } else {
    int tid = ty * 32 + tx;
    int i = ((bx - 3584) * 256 + tid) * 4;
    f32x4 v = *(const f32x4*)(W1 + i);
    ushort4 s;
    s.x = f2bf(v[0]); s.y = f2bf(v[1]); s.z = f2bf(v[2]); s.w = f2bf(v[3]);
    *(ushort4*)(W1h + i) = s;
  }
}

// ---------------------------------------------------------------- fwd + weff (coalesced, LDS-staged)
// fwd[c][m] = SC * sum_k word[c][k]*W2[m][k]  (SC = 2*log2e)
__global__ __launch_bounds__(256) void k_fwdweff(const float* __restrict__ word,
                                                 const float* __restrict__ W2,
                                                 float* __restrict__ fwd,
                                                 const float* __restrict__ Wa,
                                                 const float* __restrict__ W3,
                                                 float* __restrict__ partial) {
  __shared__ __align__(16) float w2s[64 * DWORD];   // 76.8 KB
  __shared__ __align__(16) float wds[16 * DWORD];   // 19.2 KB
  int bx = blockIdx.x, t = threadIdx.x;
  if (bx < 80) {
    int m0 = (bx & 15) * 64, c0 = (bx >> 4) * 16;
    const float SC = 2.8853900817779268f;  // 2*log2(e)
    for (int u = t; u < 64 * 75; u += 256) {
      int r = u / 75, q = u - r * 75;
      *(f32x4*)&w2s[r * DWORD + q * 4] =
          *(const f32x4*)(W2 + (size_t)(m0 + r) * DWORD + q * 4);
    }
    for (int u = t; u < 16 * 75; u += 256) {
      int r = u / 75, q = u - r * 75;
      f32x4 v = *(const f32x4*)(word + (size_t)(c0 + r) * DWORD + q * 4);
      *(f32x4*)&wds[r * DWORD + q * 4] = v * SC;
    }
    __syncthreads();
    int ci = t >> 4, mi = t & 15;
    f32x4 a0 = {0.f, 0.f, 0.f, 0.f}, a1 = a0, a2 = a0, a3 = a0;
    const float* wr = &wds[ci * DWORD];
    for (int q = 0; q < 75; ++q) {
      f32x4 wv = *(const f32x4*)&wr[q * 4];
      f32x4 b0 = *(const f32x4*)&w2s[(mi)*DWORD + q * 4];
      f32x4 b1 = *(const f32x4*)&w2s[(mi + 16) * DWORD + q * 4];
      f32x4 b2 = *(const f32x4*)&w2s[(mi + 32) * DWORD + q * 4];
      f32x4 b3 = *(const f32x4*)&w2s[(mi + 48) * DWORD + q * 4];
#pragma unroll
      for (int u = 0; u < 4; ++u) {
        a0[u] = fmaf(wv[u], b0[u], a0[u]);
        a1[u] = fmaf(wv[u], b1[u], a1[u]);
        a2[u] = fmaf(wv[u], b2[u], a2[u]);
        a3[u] = fmaf(wv[u], b3[u], a3[u]);
      }
    }
    float* dst = fwd + (size_t)(c0 + ci) * DMID + m0 + mi;
    dst[0]  = a0[0] + a0[1] + a0[2] + a0[3];
    dst[16] = a1[0] + a1[1] + a1[2] + a1[3];
    dst[32] = a2[0] + a2[1] + a2[2] + a2[3];
    dst[48] = a3[0] + a3[1] + a3[2] + a3[3];
  } else {
    int idx = bx - 80;
    int m = (idx & 3) * 256 + t;
    int n0 = (idx >> 2) * 64;
    float acc = 0.f;
    for (int n = n0; n < n0 + 64; ++n) acc = fmaf(Wa[n], W3[(size_t)n * DMID + m], acc);
    partial[(size_t)(idx >> 2) * DMID + m] = acc;
  }
}

// ---------------------------------------------------------------- FUSED: MFMA fwh-tile + sigmoid-sum -> coefp[mz]
// block (px, mz): X[64p][64m] = fmapH[p0:+64][:] x W1h[n0:+64][:]^T, then
// coefp[mz][p][c] = sum_m (-2 w[m]) / (1 + e^{X[p][m]*fwd[c][m]})
#define GLDS(g, l) \
  __builtin_amdgcn_global_load_lds((const __attribute__((address_space(1))) void*)(g), \
                                   (__attribute__((address_space(3))) void*)(l), 16, 0, 0)

__global__ __launch_bounds__(256) void k_fused(const unsigned short* __restrict__ A,
                                               const unsigned short* __restrict__ Bw,
                                               const float* __restrict__ fwd,
                                               const float* __restrict__ partial,
                                               float* __restrict__ coefp) {
  __shared__ __align__(16) char smem[49152];           // union: 48 KB
  unsigned short* As = (unsigned short*)smem;          // [3][4096] ushort (24 KB)
  unsigned short* Bs = As + 3 * 4096;                  // [3][4096] ushort (24 KB)
  float* Xl = (float*)smem;                            // [64][68] f32 (17.4 KB)
  float* bl = Xl + 64 * 68;                            // [80][68] f32 (21.8 KB)
  float* wl = bl + 80 * 68;                            // [64] f32
  int p0 = blockIdx.x * 64, mz = blockIdx.y;
  int n0 = mz * 64;
  int t = threadIdx.x;
  int w = t >> 6, l = t & 63;
  int wr = w >> 1, wc = w & 1;
  f32x4 zero = {0.f, 0.f, 0.f, 0.f};
  f32x4 acc00 = zero, acc01 = zero, acc10 = zero, acc11 = zero;

  int r0 = t >> 3, cch = t & 7;
  int r1 = r0 + 32;
  const unsigned short* ga0 = A + (size_t)(p0 + r0) * 2048 + ((cch ^ (r0 & 7)) << 3);
  const unsigned short* ga1 = A + (size_t)(p0 + r1) * 2048 + ((cch ^ (r1 & 7)) << 3);
  const unsigned short* gb0 = Bw + (size_t)(n0 + r0) * 2048 + ((cch ^ (r0 & 7)) << 3);
  const unsigned short* gb1 = Bw + (size_t)(n0 + r1) * 2048 + ((cch ^ (r1 & 7)) << 3);

  int ra = wr * 32 + (l & 15);
  int rb = wc * 32 + (l & 15);
  int cc = l >> 4;
  int a_k0 = ra * 64 + (((cc) ^ (ra & 7)) << 3);
  int a_k1 = ra * 64 + (((cc + 4) ^ (ra & 7)) << 3);
  int b_k0 = rb * 64 + (((cc) ^ (rb & 7)) << 3);
  int b_k1 = rb * 64 + (((cc + 4) ^ (rb & 7)) << 3);

#define STAGE(bi, kk) do { \
    GLDS(ga0 + (kk), As + (bi) * 4096 + t * 8); \
    GLDS(ga1 + (kk), As + (bi) * 4096 + t * 8 + 2048); \
    GLDS(gb0 + (kk), Bs + (bi) * 4096 + t * 8); \
    GLDS(gb1 + (kk), Bs + (bi) * 4096 + t * 8 + 2048); \
  } while (0)

#define COMPUTE(bi) do { \
    const unsigned short* ap = As + (bi) * 4096; \
    const unsigned short* bp = Bs + (bi) * 4096; \
    bf16x8 A0 = *(const bf16x8*)(ap + a_k0); \
    bf16x8 A1 = *(const bf16x8*)(ap + a_k0 + 1024); \
    bf16x8 B0 = *(const bf16x8*)(bp + b_k0); \
    bf16x8 B1 = *(const bf16x8*)(bp + b_k0 + 1024); \
    acc00 = __builtin_amdgcn_mfma_f32_16x16x32_bf16(A0, B0, acc00, 0, 0, 0); \
    acc01 = __builtin_amdgcn_mfma_f32_16x16x32_bf16(A0, B1, acc01, 0, 0, 0); \
    acc10 = __builtin_amdgcn_mfma_f32_16x16x32_bf16(A1, B0, acc10, 0, 0, 0); \
    acc11 = __builtin_amdgcn_mfma_f32_16x16x32_bf16(A1, B1, acc11, 0, 0, 0); \
    bf16x8 A2 = *(const bf16x8*)(ap + a_k1); \
    bf16x8 A3 = *(const bf16x8*)(ap + a_k1 + 1024); \
    bf16x8 B2 = *(const bf16x8*)(bp + b_k1); \
    bf16x8 B3 = *(const bf16x8*)(bp + b_k1 + 1024); \
    acc00 = __builtin_amdgcn_mfma_f32_16x16x32_bf16(A2, B2, acc00, 0, 0, 0); \
    acc01 = __builtin_amdgcn_mfma_f32_16x16x32_bf16(A2, B3, acc01, 0, 0, 0); \
    acc10 = __builtin_amdgcn_mfma_f32_16x16x32_bf16(A3, B2, acc10, 0, 0, 0); \
    acc11 = __builtin_amdgcn_mfma_f32_16x16x32_bf16(A3, B3, acc11, 0, 0, 0); \
  } while (0)

  STAGE(0, 0);
  STAGE(1, 64);
  asm volatile("s_waitcnt vmcnt(4)" ::: "memory");
  __builtin_amdgcn_s_barrier();
  __builtin_amdgcn_sched_barrier(0);
  for (int kt = 0; kt < 32; ++kt) {
    int cur = kt % 3;
    if (kt < 30) STAGE((kt + 2) % 3, (kt + 2) * 64);
    COMPUTE(cur);
    if (kt < 30) {
      asm volatile("s_waitcnt vmcnt(4)" ::: "memory");
      __builtin_amdgcn_s_barrier();
      __builtin_amdgcn_sched_barrier(0);
    } else if (kt == 30) {
      asm volatile("s_waitcnt vmcnt(0)" ::: "memory");
      __builtin_amdgcn_s_barrier();
      __builtin_amdgcn_sched_barrier(0);
    }
  }
  __syncthreads();   // all waves done with As/Bs -> safe to overwrite union

  // write X tile to LDS (pad 68 -> 2-way banks, free)
  {
    int cr = (l >> 4) << 2, ccn = l & 15;
#pragma unroll
    for (int q = 0; q < 4; ++q) {
      Xl[(wr * 32 + cr + q) * 68 + wc * 32 + ccn]      = acc00[q];
      Xl[(wr * 32 + cr + q) * 68 + wc * 32 + 16 + ccn] = acc01[q];
      Xl[(wr * 32 + 16 + cr + q) * 68 + wc * 32 + ccn]      = acc10[q];
      Xl[(wr * 32 + 16 + cr + q) * 68 + wc * 32 + 16 + ccn] = acc11[q];
    }
    // stage fwd slice [80][64] (prescaled) and wl[m] = -2*sum_s partial
#pragma unroll
    for (int i = 0; i < 5; ++i) {
      int idx = t + 256 * i;
      int r = idx >> 4, c4 = (idx & 15) << 2;
      *(f32x4*)&bl[r * 68 + c4] = *(const f32x4*)(fwd + (size_t)r * DMID + n0 + c4);
    }
    if (t < 64) {
      float v = 0.f;
#pragma unroll
      for (int s = 0; s < 16; ++s) v += partial[(size_t)s * DMID + n0 + t];
      wl[t] = -2.f * v;
    }
  }
  __syncthreads();

  // sigmoid-sum: m-outer, c-inner; acc[4 p-reps][5 c-chunks], statically unrolled
  int pi = t >> 4, ci = t & 15;
  float acc[4][5];
#pragma unroll
  for (int j = 0; j < 4; ++j)
#pragma unroll
    for (int k = 0; k < 5; ++k) acc[j][k] = 0.f;

#pragma unroll 1
  for (int mm = 0; mm < 64; mm += 4) {
    f32x4 wv = *(const f32x4*)&wl[mm];
    f32x4 av0 = *(const f32x4*)&Xl[(pi)*68 + mm];
    f32x4 av1 = *(const f32x4*)&Xl[(pi + 16) * 68 + mm];
    f32x4 av2 = *(const f32x4*)&Xl[(pi + 32) * 68 + mm];
    f32x4 av3 = *(const f32x4*)&Xl[(pi + 48) * 68 + mm];
#pragma unroll
    for (int k = 0; k < 5; ++k) {
      f32x4 bv = *(const f32x4*)&bl[(k * 16 + ci) * 68 + mm];
#pragma unroll
      for (int u = 0; u < 4; ++u) {
        float wgt = wv[u], b = bv[u];
        float e0 = __builtin_amdgcn_exp2f(av0[u] * b);
        float e1 = __builtin_amdgcn_exp2f(av1[u] * b);
        float e2 = __builtin_amdgcn_exp2f(av2[u] * b);
        float e3 = __builtin_amdgcn_exp2f(av3[u] * b);
        acc[0][k] = fmaf(wgt, __builtin_amdgcn_rcpf(1.f + e0), acc[0][k]);
        acc[1][k] = fmaf(wgt, __builtin_amdgcn_rcpf(1.f + e1), acc[1][k]);
        acc[2][k] = fmaf(wgt, __builtin_amdgcn_rcpf(1.f + e2), acc[2][k]);
        acc[3][k] = fmaf(wgt, __builtin_amdgcn_rcpf(1.f + e3), acc[3][k]);
      }
    }
  }
  float* cp = coefp + (size_t)mz * (PN * NC);
#pragma unroll
  for (int j = 0; j < 4; ++j) {
    int p = p0 + pi + 16 * j;
    if (p < PN) {
#pragma unroll
      for (int k = 0; k < 5; ++k)
        cp[(size_t)p * NC + k * 16 + ci] = acc[j][k];
    }
  }
#undef STAGE
#undef COMPUTE
}

// ---------------------------------------------------------------- softmax + pooling; reads img directly
__global__ __launch_bounds__(256) void k_pool(const float* __restrict__ coefp,
                                              const float* __restrict__ img,
                                              float* __restrict__ out) {
  __shared__ __align__(16) float wt[HWN][16];
  __shared__ float red[16][16];
  __shared__ float mxs[16], inv[16];
  int dc = blockIdx.x * 256, cg = blockIdx.y * 16, b = blockIdx.z;
  int t = threadIdx.x;
  for (int i = t; i < HWN * 4; i += 256) {
    int hw = i >> 2, j4 = (i & 3) << 2;
    size_t o = (size_t)(b * HWN + hw) * NC + cg + j4;
    f32x4 s = {0.f, 0.f, 0.f, 0.f};
#pragma unroll
    for (int z = 0; z < PART; ++z) s += *(const f32x4*)&coefp[o + (size_t)z * (PN * NC)];
    *(f32x4*)&wt[hw][j4] = s;
  }
  __syncthreads();
  int j = t & 15, g = t >> 4;
  float pm = -1e30f;
  for (int hw = g; hw < HWN; hw += 16) pm = fmaxf(pm, wt[hw][j]);
  red[g][j] = pm;
  __syncthreads();
  if (t < 16) {
    float m = red[0][t];
#pragma unroll
    for (int g2 = 1; g2 < 16; ++g2) m = fmaxf(m, red[g2][t]);
    mxs[t] = m;
  }
  __syncthreads();
  float mj = mxs[j], ps = 0.f;
  for (int hw = g; hw < HWN; hw += 16) {
    float e = __builtin_amdgcn_exp2f((wt[hw][j] - mj) * 1.4426950408889634f);
    wt[hw][j] = e;
    ps += e;
  }
  red[g][j] = ps;
  __syncthreads();
  if (t < 16) {
    float s = 0.f;
#pragma unroll
    for (int g2 = 0; g2 < 16; ++g2) s += red[g2][t];
    inv[t] = 1.f / s;
  }
  __syncthreads();
  float acc[16];
#pragma unroll
  for (int q = 0; q < 16; ++q) acc[q] = 0.f;
  const float* fpd = img + ((size_t)b * DIMG + dc + t) * HWN;  // contiguous 196-row per thread
  for (int hw = 0; hw < HWN; ++hw) {
    float v = fpd[hw];
#pragma unroll
    for (int q = 0; q < 16; ++q) acc[q] = fmaf(wt[hw][q], v, acc[q]);
  }
#pragma unroll
  for (int q = 0; q < 16; ++q)
    out[((size_t)b * NC + cg + q) * DIMG + dc + t] = acc[q] * inv[q];
}

// ----------------------------------------------------------------
extern "C" void kernel_launch(void* const* d_in, const int* in_sizes, int n_in,
                              void* d_out, int out_size, void* d_ws, size_t ws_size,
                              hipStream_t stream) {
  const float* img  = (const float*)d_in[1];
  const float* word = (const float*)d_in[2];
  const float* W1   = (const float*)d_in[3];
  const float* W2   = (const float*)d_in[4];
  const float* W3   = (const float*)d_in[5];
  const float* Wa   = (const float*)d_in[7];
  // b3 (d_in[6]) and ba (d_in[8]) are softmax-shift-invariant -> dropped.
  float* out = (float*)d_out;
  char* ws = (char*)d_ws;

  unsigned short* fmapH   = (unsigned short*)(ws + 0);         // 1600*2048*2 = 6,553,600
  unsigned short* W1h     = (unsigned short*)(ws + 6553600);   // 1024*2048*2 = 4,194,304
  float*          fwd     = (float*)(ws + 10747904);           //  96*1024*4 =   393,216
  float*          partial = (float*)(ws + 11141120);           //  16*1024*4 =    65,536
  float*          coefp   = (float*)(ws + 11206656);           // 16*1568*80*4 = 8,028,160

  hipLaunchKernelGGL(k_tc, dim3(5632), dim3(32, 8), 0, stream, img, fmapH, W1, W1h);
  hipLaunchKernelGGL(k_fwdweff, dim3(144), dim3(256), 0, stream,
                     word, W2, fwd, Wa, W3, partial);
  hipLaunchKernelGGL(k_fused, dim3(25, 16), dim3(256), 0, stream,
                     fmapH, W1h, fwd, partial, coefp);
  hipLaunchKernelGGL(k_pool, dim3(8, 5, 8), dim3(256), 0, stream, coefp, img, out);
  (void)in_sizes; (void)n_in; (void)out_size; (void)ws_size;
}